// Round 4
// baseline (26170.850 us; speedup 1.0000x reference)
//
#include <hip/hip_runtime.h>
#include <hip/hip_bf16.h>

// ---------------------------------------------------------------------------
// Bidirectional 2-layer LSTM (B=128, T=512, H=256, INPUT=4) + mean-pool + FC.
//
// Round-4: cross-block exchange ELIMINATED. One block owns ALL 1024 gate
// columns for a 16-row batch slice; h(t-1) lives in swizzled LDS (parity
// double buffer); weights are pre-converted to bf16 and streamed from L2
// every step (step-invariant -> L2-hot). One barrier per step, no atomics,
// no flags, no polls.
//   k_l0: 16 blocks (dir x 8 slices) x 512 thr. K=256. Exports h0/step.
//   k_l1: 16 blocks x 512 thr. K=768 = [h1_prev(LDS) | h0f | h0b (global)].
//         h1 ring / flags / gate-exchange all gone; pool in registers.
// ws: h0 [2][513][128][256] bf16 (67.2MB) | pooled f32 256KB | bf16 weights
//     (wb0 1MB, w1h 1MB, w1i 2MB)  -> total ~71.7MB.
// ---------------------------------------------------------------------------

typedef __bf16 bf16;
typedef __bf16 bf16x8 __attribute__((ext_vector_type(8)));
typedef float  f32x4  __attribute__((ext_vector_type(4)));
typedef unsigned int u32;

#define T_SEQ 512
#define BATCH 128
#define HID   256

#define H0_BYTES   67239936ULL                  // bf16 [2][513][128][256]
#define POOL_OFF   H0_BYTES                     // f32 [2][128][256] = 262144 B
#define WB0_OFF    (H0_BYTES + 262144ULL)       // bf16 Whh0 [2][1024][256] = 1MB
#define W1H_OFF    (WB0_OFF + 1048576ULL)       // bf16 Whh1 [2][1024][256] = 1MB
#define W1I_OFF    (W1H_OFF + 1048576ULL)       // bf16 Wih1 [2][1024][512] = 2MB

#define MFMA16(a, b, c) __builtin_amdgcn_mfma_f32_16x16x32_bf16((a), (b), (c), 0, 0, 0)

__device__ __forceinline__ float fsig(float v) {
    return __builtin_amdgcn_rcpf(1.0f + __expf(-v));
}
__device__ __forceinline__ float ftanh(float v) {
    float a = fabsf(v);
    float e = __expf(-2.0f * a);
    float r = (1.0f - e) * __builtin_amdgcn_rcpf(1.0f + e);
    return v < 0.0f ? -r : r;
}

// 8 n-frags x 8 kt GEMM section with 2-deep B prefetch. A: av[kt]; B: wp[f]
// (element pointers, already include +q*8); koff = extra K element offset.
__device__ __forceinline__ void gemm8(f32x4 (&acc)[8], const bf16x8 (&av)[8],
                                      const bf16* const (&wp)[8], const int koff)
{
    bf16x8 Ba[8], Bb[8];
#pragma unroll
    for (int f = 0; f < 8; ++f) Ba[f] = *(const bf16x8*)(wp[f] + koff);
#pragma unroll
    for (int kt = 0; kt < 8; kt += 2) {
#pragma unroll
        for (int f = 0; f < 8; ++f) Bb[f] = *(const bf16x8*)(wp[f] + koff + (kt + 1) * 32);
#pragma unroll
        for (int f = 0; f < 8; ++f) acc[f] = MFMA16(av[kt], Ba[f], acc[f]);
        if (kt + 2 < 8) {
#pragma unroll
            for (int f = 0; f < 8; ++f) Ba[f] = *(const bf16x8*)(wp[f] + koff + (kt + 2) * 32);
        }
#pragma unroll
        for (int f = 0; f < 8; ++f) acc[f] = MFMA16(av[kt + 1], Bb[f], acc[f]);
    }
}

// ---------------------------------------------------------------------------
// k_init: pre-convert recurrent/input weights to bf16 (layouts unchanged).
// ---------------------------------------------------------------------------
__global__ void k_init(const float* __restrict__ whh0, const float* __restrict__ whh1,
                       const float* __restrict__ wih1,
                       bf16* __restrict__ wb0, bf16* __restrict__ w1h,
                       bf16* __restrict__ w1i)
{
    const int t = blockIdx.x * 256 + threadIdx.x;
    const int stride = gridDim.x * 256;
    for (int i = t; i < 2 * 1024 * 256; i += stride) wb0[i] = (bf16)whh0[i];
    for (int i = t; i < 2 * 1024 * 256; i += stride) w1h[i] = (bf16)whh1[i];
    for (int i = t; i < 2 * 1024 * 512; i += stride) w1i[i] = (bf16)wih1[i];
}

// ---------------------------------------------------------------------------
// Layer 0: 16 blocks = slice(8) x dir(2). 512 thr = 8 waves. Per block:
// M=16 rows, N=1024 (full 4H), K=256. Wave w owns cols {tg*256 + w*32 +
// u*16 + l15 : tg<4, u<2} -> self-contained cell update. h(t-1) in LDS.
// ---------------------------------------------------------------------------
__global__ __launch_bounds__(512, 2) void k_l0(
    const float* __restrict__ x, const float* __restrict__ wih,
    const float* __restrict__ bih, const float* __restrict__ bhh,
    const bf16* __restrict__ wb, bf16* __restrict__ h0)
{
    __shared__ __align__(16) char Hp[2 * 8192];    // [parity][16 rows][512B] swizzled

    const int blk = blockIdx.x;
    const int dir = blk & 1, bs = blk >> 1;
    const int tid = threadIdx.x, w = tid >> 6, lane = tid & 63;
    const int l15 = lane & 15, q = lane >> 4;

    const bf16* wp[8];
    float biasg[8], wx[8][4];
#pragma unroll
    for (int tg = 0; tg < 4; ++tg) {
#pragma unroll
        for (int u = 0; u < 2; ++u) {
            const int f = tg * 2 + u;
            const int n = dir * 1024 + tg * 256 + w * 32 + u * 16 + l15;
            wp[f] = wb + (size_t)n * 256 + q * 8;
            biasg[f] = bih[n] + bhh[n];
#pragma unroll
            for (int d = 0; d < 4; ++d) wx[f][d] = wih[(size_t)n * 4 + d];
        }
    }

    // zero parity-0 h (h(0) = 0); swizzle-invariant since all zeros
#pragma unroll
    for (int i = 0; i < 4; ++i) ((u32*)Hp)[tid * 4 + i] = 0u;
    __syncthreads();

    float c4[2][4] = {};
#pragma unroll 1
    for (int s = 1; s <= T_SEQ; ++s) {
        const int t_in = dir ? (T_SEQ - s) : (s - 1);
        char* hbp = Hp + ((s - 1) & 1) * 8192;
        char* hbc = Hp + (s & 1) * 8192;

        // gx = bias + x(t).Wih (VALU; x is L1/L2-hot)
        f32x4 xv[4];
#pragma unroll
        for (int r = 0; r < 4; ++r)
            xv[r] = *(const f32x4*)(x + ((size_t)(bs * 16 + q * 4 + r) * T_SEQ + t_in) * 4);
        f32x4 acc[8];
#pragma unroll
        for (int f = 0; f < 8; ++f)
#pragma unroll
            for (int r = 0; r < 4; ++r)
                acc[f][r] = biasg[f] + xv[r][0] * wx[f][0] + xv[r][1] * wx[f][1]
                                     + xv[r][2] * wx[f][2] + xv[r][3] * wx[f][3];

        // A fragments: h(t-1) from swizzled LDS
        bf16x8 av[8];
#pragma unroll
        for (int kt = 0; kt < 8; ++kt)
            av[kt] = *(const bf16x8*)(hbp + l15 * 512 + ((kt * 64 + q * 16) ^ ((l15 & 7) << 4)));

        gemm8(acc, av, wp, 0);                 // h(t-1) x Whh (B streamed from L2)

        // cell update -> swizzled LDS h(t)
#pragma unroll
        for (int u = 0; u < 2; ++u) {
            const int hid2 = (w * 32 + u * 16 + l15) * 2;
#pragma unroll
            for (int r = 0; r < 4; ++r) {
                const float iv = fsig(acc[0 + u][r]);
                const float fv = fsig(acc[2 + u][r]);
                const float gv = ftanh(acc[4 + u][r]);
                const float ov = fsig(acc[6 + u][r]);
                c4[u][r] = fv * c4[u][r] + iv * gv;
                const float hv = ov * ftanh(c4[u][r]);
                const int row = q * 4 + r;
                *(bf16*)(hbc + row * 512 + (hid2 ^ ((row & 7) << 4))) = (bf16)hv;
            }
        }
        __syncthreads();

        // export h(t) to global h0 (plain coalesced stores; k_l1 runs after)
        {
            const int row = tid >> 5, cg = tid & 31;
            const bf16x8 v = *(const bf16x8*)(hbc + row * 512 + ((cg * 16) ^ ((row & 7) << 4)));
            *(bf16x8*)(h0 + ((size_t)(dir * 513 + s) * BATCH + bs * 16 + row) * HID + cg * 8) = v;
        }
    }
}

// ---------------------------------------------------------------------------
// Layer 1: 16 blocks = slice(8) x dir(2). 512 thr. Per block: M=16, N=1024,
// K=768 = [h1_prev (LDS) | h0f | h0b (global, L1-hot)]. Pool in registers.
// ---------------------------------------------------------------------------
__global__ __launch_bounds__(512, 2) void k_l1(
    const float* __restrict__ bih1, const float* __restrict__ bhh1,
    const bf16* __restrict__ w1h, const bf16* __restrict__ w1i,
    const bf16* __restrict__ h0, float* __restrict__ pooled)
{
    __shared__ __align__(16) char Hp[2 * 8192];    // h1(t-1) swizzled parity dbuf

    const int blk = blockIdx.x;
    const int dir = blk & 1, bs = blk >> 1;
    const int tid = threadIdx.x, w = tid >> 6, lane = tid & 63;
    const int l15 = lane & 15, q = lane >> 4;

    const bf16* wph[8];
    const bf16* wpi[8];
    float biasw[8];
#pragma unroll
    for (int tg = 0; tg < 4; ++tg) {
#pragma unroll
        for (int u = 0; u < 2; ++u) {
            const int f = tg * 2 + u;
            const int n = dir * 1024 + tg * 256 + w * 32 + u * 16 + l15;
            wph[f] = w1h + (size_t)n * 256 + q * 8;
            wpi[f] = w1i + (size_t)n * 512 + q * 8;
            biasw[f] = bih1[n] + bhh1[n];
        }
    }

#pragma unroll
    for (int i = 0; i < 4; ++i) ((u32*)Hp)[tid * 4 + i] = 0u;
    __syncthreads();

    float c4[2][4] = {};
    float pool[2][4] = {};
#pragma unroll 1
    for (int s = 1; s <= T_SEQ; ++s) {
        const int slotf = dir ? (513 - s) : s;     // h0 fwd slot for time t
        const int slotb = dir ? s : (513 - s);     // h0 bwd slot for time t
        char* hbp = Hp + ((s - 1) & 1) * 8192;
        char* hbc = Hp + (s & 1) * 8192;

        // h0-fwd A fragments (global, issued early) + h1_prev (LDS)
        const bf16* f0 = h0 + ((size_t)slotf * BATCH + bs * 16 + l15) * HID + q * 8;
        const bf16* b0 = h0 + ((size_t)(513 + slotb) * BATCH + bs * 16 + l15) * HID + q * 8;
        bf16x8 avf[8];
#pragma unroll
        for (int kt = 0; kt < 8; ++kt) avf[kt] = *(const bf16x8*)(f0 + kt * 32);
        bf16x8 av1[8];
#pragma unroll
        for (int kt = 0; kt < 8; ++kt)
            av1[kt] = *(const bf16x8*)(hbp + l15 * 512 + ((kt * 64 + q * 16) ^ ((l15 & 7) << 4)));

        f32x4 acc[8];
#pragma unroll
        for (int f = 0; f < 8; ++f) {
            acc[f][0] = biasw[f]; acc[f][1] = biasw[f];
            acc[f][2] = biasw[f]; acc[f][3] = biasw[f];
        }

        gemm8(acc, av1, wph, 0);       // h1_prev x Whh1

        bf16x8 avb[8];                 // h0-bwd A issued here, hides under h0f GEMM
#pragma unroll
        for (int kt = 0; kt < 8; ++kt) avb[kt] = *(const bf16x8*)(b0 + kt * 32);

        gemm8(acc, avf, wpi, 0);       // h0 fwd x Wih1[:, 0:256]
        gemm8(acc, avb, wpi, 256);     // h0 bwd x Wih1[:, 256:512]

        // cell update + pool + h1(t) -> swizzled LDS
#pragma unroll
        for (int u = 0; u < 2; ++u) {
            const int hid2 = (w * 32 + u * 16 + l15) * 2;
#pragma unroll
            for (int r = 0; r < 4; ++r) {
                const float iv = fsig(acc[0 + u][r]);
                const float fv = fsig(acc[2 + u][r]);
                const float gv = ftanh(acc[4 + u][r]);
                const float ov = fsig(acc[6 + u][r]);
                c4[u][r] = fv * c4[u][r] + iv * gv;
                const float hv = ov * ftanh(c4[u][r]);
                pool[u][r] += hv;
                const int row = q * 4 + r;
                *(bf16*)(hbc + row * 512 + (hid2 ^ ((row & 7) << 4))) = (bf16)hv;
            }
        }
        __syncthreads();
    }

    // mean-pool epilogue
#pragma unroll
    for (int u = 0; u < 2; ++u)
#pragma unroll
        for (int r = 0; r < 4; ++r)
            pooled[((size_t)dir * BATCH + bs * 16 + q * 4 + r) * HID + (w * 32 + u * 16 + l15)] =
                pool[u][r] * (1.0f / 512.0f);
}

// ---------------------------------------------------------------------------
__global__ void k_fc(const float* __restrict__ pooled, const float* __restrict__ fcw,
                     const float* __restrict__ fcb, float* __restrict__ out)
{
    const int b = blockIdx.x;            // 128 blocks, 64 threads
    const int lane = threadIdx.x;
    float s0 = 0.f, s1 = 0.f;
#pragma unroll
    for (int jj = 0; jj < 8; ++jj) {
        const int jx = lane + jj * 64;   // 0..511
        const float p = (jx < 256) ? pooled[(size_t)b * 256 + jx]
                                   : pooled[32768 + (size_t)b * 256 + (jx - 256)];
        s0 += p * fcw[jx];
        s1 += p * fcw[512 + jx];
    }
#pragma unroll
    for (int off = 32; off > 0; off >>= 1) {
        s0 += __shfl_down(s0, off);
        s1 += __shfl_down(s1, off);
    }
    if (lane == 0) {
        out[b * 2 + 0] = s0 + fcb[0];
        out[b * 2 + 1] = s1 + fcb[1];
    }
}

// ---------------------------------------------------------------------------
extern "C" void kernel_launch(void* const* d_in, const int* in_sizes, int n_in,
                              void* d_out, int out_size, void* d_ws, size_t ws_size,
                              hipStream_t stream)
{
    const float* x    = (const float*)d_in[0];
    const float* wih0 = (const float*)d_in[1];
    const float* whh0 = (const float*)d_in[2];
    const float* bih0 = (const float*)d_in[3];
    const float* bhh0 = (const float*)d_in[4];
    const float* wih1 = (const float*)d_in[5];
    const float* whh1 = (const float*)d_in[6];
    const float* bih1 = (const float*)d_in[7];
    const float* bhh1 = (const float*)d_in[8];
    const float* fcw  = (const float*)d_in[9];
    const float* fcb  = (const float*)d_in[10];
    float* out = (float*)d_out;

    char* ws = (char*)d_ws;
    bf16* h0      = (bf16*)ws;
    float* pooled = (float*)(ws + POOL_OFF);
    bf16* wb0     = (bf16*)(ws + WB0_OFF);
    bf16* w1h     = (bf16*)(ws + W1H_OFF);
    bf16* w1i     = (bf16*)(ws + W1I_OFF);

    k_init<<<dim3(512), dim3(256), 0, stream>>>(whh0, whh1, wih1, wb0, w1h, w1i);
    k_l0<<<dim3(16), dim3(512), 0, stream>>>(x, wih0, bih0, bhh0, wb0, h0);
    k_l1<<<dim3(16), dim3(512), 0, stream>>>(bih1, bhh1, w1h, w1i, h0, pooled);
    k_fc<<<dim3(128), dim3(64), 0, stream>>>(pooled, fcw, fcb, out);
}